// Round 1
// baseline (1126.691 us; speedup 1.0000x reference)
//
#include <hip/hip_runtime.h>
#include <hip/hip_bf16.h>

#define B_ 2
#define S_ 2048
#define D_ 4096
#define H_ 32
#define KV_ 8
#define HD_ 128

typedef __attribute__((ext_vector_type(8))) short sh8;
typedef __attribute__((ext_vector_type(4))) float f32x4;

__device__ __forceinline__ float b2f(unsigned short u) {
    union { unsigned int i; float f; } v; v.i = ((unsigned)u) << 16; return v.f;
}
__device__ __forceinline__ unsigned short f2b(float f) {
    union { float f; unsigned int i; } v; v.f = f;
    unsigned r = v.i + 0x7fffu + ((v.i >> 16) & 1u);
    return (unsigned short)(r >> 16);
}
__device__ __forceinline__ void gload_lds16(const void* g, void* l) {
    __builtin_amdgcn_global_load_lds((const __attribute__((address_space(1))) void*)g,
                                     (__attribute__((address_space(3))) void*)l, 16, 0, 0);
}

// ---------------- fp32 -> bf16 convert ----------------
__global__ __launch_bounds__(256) void f2b_kernel(const float* __restrict__ in,
                                                  unsigned short* __restrict__ out, int n8) {
    int t = blockIdx.x * 256 + threadIdx.x;
    if (t >= n8) return;
    const float* p = in + (size_t)t * 8;
    float4 a = *(const float4*)p;
    float4 b = *(const float4*)(p + 4);
    sh8 o;
    o[0] = (short)f2b(a.x); o[1] = (short)f2b(a.y); o[2] = (short)f2b(a.z); o[3] = (short)f2b(a.w);
    o[4] = (short)f2b(b.x); o[5] = (short)f2b(b.y); o[6] = (short)f2b(b.z); o[7] = (short)f2b(b.w);
    *(sh8*)(out + (size_t)t * 8) = o;
}

// ---------------- GEMM: C[M,N] = A[M,K] * B[N,K]^T (m97 structure) ----------------
__device__ __forceinline__ void cstore(float* C, size_t i, float v) { C[i] = v; }
__device__ __forceinline__ void cstore(unsigned short* C, size_t i, float v) { C[i] = f2b(v); }

template <typename CT>
__global__ __launch_bounds__(256) void gemm_bt_kernel(const unsigned short* __restrict__ A,
                                                      const unsigned short* __restrict__ Bm,
                                                      CT* __restrict__ C, int M, int N, int K) {
    __shared__ __align__(16) unsigned short As[128 * 32];
    __shared__ __align__(16) unsigned short Bs[128 * 32];
    int nwg = gridDim.x;
    int wg = blockIdx.x;
    int cpx = nwg >> 3;                       // grids are %8==0
    int swz = (wg & 7) * cpx + (wg >> 3);     // XCD-aware swizzle (bijective)
    int nbn = N >> 7;
    int bm = swz / nbn, bn = swz % nbn;
    int t = threadIdx.x, w = t >> 6, l = t & 63;
    int wm = w >> 1, wn = w & 1;
    int fr = l & 15, fq = l >> 4;
    f32x4 acc[4][4];
#pragma unroll
    for (int i = 0; i < 4; i++)
#pragma unroll
        for (int j = 0; j < 4; j++) acc[i][j] = (f32x4){0.f, 0.f, 0.f, 0.f};
    const size_t rowA0 = (size_t)bm * 128, rowB0 = (size_t)bn * 128;
    int lrow = l >> 2;
    int lcb = (l & 3) * 16;
    for (int k0 = 0; k0 < K; k0 += 32) {
#pragma unroll
        for (int r = 0; r < 2; ++r) {
            int chunk = r * 4 + w;
            int row = chunk * 16 + lrow;
            const char* ga = (const char*)(A + (rowA0 + row) * (size_t)K + k0) + lcb;
            gload_lds16(ga, (char*)As + chunk * 1024);
            const char* gb = (const char*)(Bm + (rowB0 + row) * (size_t)K + k0) + lcb;
            gload_lds16(gb, (char*)Bs + chunk * 1024);
        }
        __syncthreads();
        sh8 af[4], bfv[4];
#pragma unroll
        for (int mi = 0; mi < 4; mi++) af[mi] = *(const sh8*)(As + (wm * 64 + mi * 16 + fr) * 32 + fq * 8);
#pragma unroll
        for (int ni = 0; ni < 4; ni++) bfv[ni] = *(const sh8*)(Bs + (wn * 64 + ni * 16 + fr) * 32 + fq * 8);
#pragma unroll
        for (int mi = 0; mi < 4; mi++)
#pragma unroll
            for (int ni = 0; ni < 4; ni++)
                acc[mi][ni] = __builtin_amdgcn_mfma_f32_16x16x32_bf16(af[mi], bfv[ni], acc[mi][ni], 0, 0, 0);
        __syncthreads();
    }
#pragma unroll
    for (int mi = 0; mi < 4; mi++)
#pragma unroll
        for (int ni = 0; ni < 4; ni++) {
            size_t row = rowA0 + wm * 64 + mi * 16 + fq * 4;
            size_t col = rowB0 + wn * 64 + ni * 16 + fr;
#pragma unroll
            for (int j = 0; j < 4; j++) cstore(C, (row + j) * (size_t)N + col, acc[mi][ni][j]);
        }
}

// ---------------- RoPE (+ optional 1/sqrt(HD) fold) ----------------
// raw: (B*S, NH*HD) bf16; out: (B, NH, S, HD) bf16
template <int NH>
__global__ __launch_bounds__(256) void rope_kernel(const unsigned short* __restrict__ raw,
                                                   const float* __restrict__ cosb,
                                                   const float* __restrict__ sinb,
                                                   unsigned short* __restrict__ out, float scale) {
    int t = blockIdx.x * 256 + threadIdx.x;
    int g = t & 7;
    int h = (t >> 3) & (NH - 1);
    int row = t / (8 * NH);
    if (row >= B_ * S_) return;
    int b = row >> 11, s = row & (S_ - 1);
    const unsigned short* qr = raw + (size_t)row * (NH * HD_) + h * HD_ + g * 8;
    sh8 lo = *(const sh8*)qr;
    sh8 hi = *(const sh8*)(qr + 64);
    const float* cp = cosb + (size_t)row * HD_ + g * 8;
    const float* sp = sinb + (size_t)row * HD_ + g * 8;
    float4 c0 = *(const float4*)cp, c1 = *(const float4*)(cp + 4);
    float4 s0 = *(const float4*)sp, s1 = *(const float4*)(sp + 4);
    float cc[8] = {c0.x, c0.y, c0.z, c0.w, c1.x, c1.y, c1.z, c1.w};
    float ss[8] = {s0.x, s0.y, s0.z, s0.w, s1.x, s1.y, s1.z, s1.w};
    sh8 olo, ohi;
#pragma unroll
    for (int i = 0; i < 8; i++) {
        float fl = b2f((unsigned short)lo[i]);
        float fh = b2f((unsigned short)hi[i]);
        olo[i] = (short)f2b((fl * cc[i] - fh * ss[i]) * scale);
        ohi[i] = (short)f2b((fh * cc[i] + fl * ss[i]) * scale);
    }
    unsigned short* op = out + (((size_t)b * NH + h) * S_ + s) * HD_ + g * 8;
    *(sh8*)op = olo;
    *(sh8*)(op + 64) = ohi;
}

// ---------------- V transpose: (B*S, KV*HD) -> (B, KV, HD, S) ----------------
__global__ __launch_bounds__(256) void vtrans_kernel(const unsigned short* __restrict__ vraw,
                                                     unsigned short* __restrict__ vt) {
    __shared__ unsigned short tile[64][132];
    int bid = blockIdx.x;
    int st = bid & 31;
    int kv = (bid >> 5) & 7;
    int b = bid >> 8;
    int s0 = st * 64;
    int t = threadIdx.x;
    {
        int s = t >> 2, dq = (t & 3) * 32;
        const unsigned short* src = vraw + ((size_t)(b * S_ + s0 + s)) * (KV_ * HD_) + kv * HD_ + dq;
#pragma unroll
        for (int i = 0; i < 4; i++) *(sh8*)&tile[s][dq + i * 8] = *(const sh8*)(src + i * 8);
    }
    __syncthreads();
    {
        int d = t & 127, sh = t >> 7;
        unsigned short* dst = vt + (((size_t)(b * KV_ + kv)) * HD_ + d) * S_ + s0 + sh * 32;
#pragma unroll
        for (int q = 0; q < 4; q++) {
            sh8 vv;
#pragma unroll
            for (int e = 0; e < 8; e++) vv[e] = (short)tile[sh * 32 + q * 8 + e][d];
            *(sh8*)(dst + q * 8) = vv;
        }
    }
}

// ---------------- causal GQA flash attention ----------------
// Q: (B,H,S,HD) bf16 pre-scaled; Kr: (B,KV,S,HD); Vt: (B,KV,HD,S); O: (B,S,H*HD)
__global__ __launch_bounds__(256) void attn_kernel(const unsigned short* __restrict__ Q,
                                                   const unsigned short* __restrict__ Kr,
                                                   const unsigned short* __restrict__ Vt,
                                                   unsigned short* __restrict__ O) {
    __shared__ __align__(16) unsigned short Kl[64 * 128];  // [s][d] source-swizzled
    __shared__ __align__(16) unsigned short Vl[128 * 64];  // [d][s] source-swizzled
    __shared__ __align__(16) unsigned short Pl[4][16 * 72];
    int nwg = gridDim.x;
    int bid0 = blockIdx.x;
    int cpx = nwg >> 3;
    int u = (bid0 & 7) * cpx + (bid0 >> 3);   // XCD swizzle: blocks sharing (b,kv) stay on one XCD
    int qi = u & 31;
    int h = (u >> 5) & 31;
    int b = u >> 10;
    int kv = h >> 2;
    int t = threadIdx.x, w = t >> 6, l = t & 63;
    int fr = l & 15, fq = l >> 4;
    int qw = qi * 64 + w * 16;
    const unsigned short* Qp = Q + (((size_t)b * H_ + h) * S_ + qw + fr) * HD_;
    sh8 qf[4];
#pragma unroll
    for (int kk = 0; kk < 4; kk++) qf[kk] = *(const sh8*)(Qp + kk * 32 + fq * 8);
    const unsigned short* Kg = Kr + ((size_t)b * KV_ + kv) * S_ * HD_;
    const unsigned short* Vg = Vt + ((size_t)b * KV_ + kv) * HD_ * S_;
    f32x4 po[8];
#pragma unroll
    for (int i = 0; i < 8; i++) po[i] = (f32x4){0.f, 0.f, 0.f, 0.f};
    float m_r[4] = {-3.0e38f, -3.0e38f, -3.0e38f, -3.0e38f};
    float l_r[4] = {0.f, 0.f, 0.f, 0.f};
    for (int j = 0; j <= qi; ++j) {
#pragma unroll
        for (int r = 0; r < 4; ++r) {
            int chunk = r * 4 + w;
            {   // K tile: LDS slot (s, c') <- global slot (s, c'^(s&7))
                int lb = chunk * 1024 + l * 16;
                int srow = lb >> 8;
                int cs = (lb >> 4) & 15;
                int gs = cs ^ (srow & 7);
                const char* ga = (const char*)(Kg + (size_t)(j * 64 + srow) * HD_) + gs * 16;
                gload_lds16(ga, (char*)Kl + chunk * 1024);
            }
            {   // V tile: LDS slot (d, c') <- global slot (d, c'^(d&7))
                int lb = chunk * 1024 + l * 16;
                int drow = lb >> 7;
                int cs = (lb >> 4) & 7;
                int gs = cs ^ (drow & 7);
                const char* gv = (const char*)(Vg + (size_t)drow * S_ + j * 64 + gs * 8);
                gload_lds16(gv, (char*)Vl + chunk * 1024);
            }
        }
        __syncthreads();
        // S = Q K^T  (16 q-rows x 64 kv per wave)
        f32x4 sacc[4];
#pragma unroll
        for (int nc = 0; nc < 4; nc++) {
            sacc[nc] = (f32x4){0.f, 0.f, 0.f, 0.f};
            int n = nc * 16 + fr;
#pragma unroll
            for (int kk = 0; kk < 4; kk++) {
                sh8 kf = *(const sh8*)(Kl + n * 128 + (((kk * 4 + fq) ^ (n & 7)) * 8));
                sacc[nc] = __builtin_amdgcn_mfma_f32_16x16x32_bf16(qf[kk], kf, sacc[nc], 0, 0, 0);
            }
        }
        if (j == qi) {
#pragma unroll
            for (int nc = 0; nc < 4; nc++) {
                int kg = j * 64 + nc * 16 + fr;
#pragma unroll
                for (int j3 = 0; j3 < 4; j3++) {
                    int qg = qw + fq * 4 + j3;
                    if (kg > qg) sacc[nc][j3] = -1e30f;
                }
            }
        }
        float pb[4][4];
#pragma unroll
        for (int j3 = 0; j3 < 4; j3++) {
            float tm = sacc[0][j3];
#pragma unroll
            for (int nc = 1; nc < 4; nc++) tm = fmaxf(tm, sacc[nc][j3]);
            tm = fmaxf(tm, __shfl_xor(tm, 1));
            tm = fmaxf(tm, __shfl_xor(tm, 2));
            tm = fmaxf(tm, __shfl_xor(tm, 4));
            tm = fmaxf(tm, __shfl_xor(tm, 8));
            float newm = fmaxf(m_r[j3], tm);
            float alpha = __expf(m_r[j3] - newm);
            float rs = 0.f;
#pragma unroll
            for (int nc = 0; nc < 4; nc++) {
                float p = __expf(sacc[nc][j3] - newm);
                pb[nc][j3] = p;
                rs += p;
            }
            rs += __shfl_xor(rs, 1);
            rs += __shfl_xor(rs, 2);
            rs += __shfl_xor(rs, 4);
            rs += __shfl_xor(rs, 8);
            l_r[j3] = l_r[j3] * alpha + rs;
            m_r[j3] = newm;
#pragma unroll
            for (int dc = 0; dc < 8; dc++) po[dc][j3] *= alpha;
        }
        unsigned short* Pw = Pl[w];
#pragma unroll
        for (int nc = 0; nc < 4; nc++)
#pragma unroll
            for (int j3 = 0; j3 < 4; j3++)
                Pw[(fq * 4 + j3) * 72 + nc * 16 + fr] = f2b(pb[nc][j3]);
        // PV
#pragma unroll
        for (int kc = 0; kc < 2; kc++) {
            sh8 pf = *(const sh8*)(Pw + fr * 72 + kc * 32 + fq * 8);
#pragma unroll
            for (int dc = 0; dc < 8; dc++) {
                int d = dc * 16 + fr;
                sh8 vf = *(const sh8*)(Vl + d * 64 + (((kc * 4 + fq) ^ (d & 7)) * 8));
                po[dc] = __builtin_amdgcn_mfma_f32_16x16x32_bf16(pf, vf, po[dc], 0, 0, 0);
            }
        }
        __syncthreads();
    }
#pragma unroll
    for (int j3 = 0; j3 < 4; j3++) {
        float inv = 1.f / l_r[j3];
        size_t orow = (size_t)b * S_ + qw + fq * 4 + j3;
#pragma unroll
        for (int dc = 0; dc < 8; dc++)
            O[orow * (H_ * HD_) + h * HD_ + dc * 16 + fr] = f2b(po[dc][j3] * inv);
    }
}

// ---------------- host launcher ----------------
extern "C" void kernel_launch(void* const* d_in, const int* in_sizes, int n_in,
                              void* d_out, int out_size, void* d_ws, size_t ws_size,
                              hipStream_t stream) {
    const float* x = (const float*)d_in[0];
    const float* wq = (const float*)d_in[1];
    const float* wk = (const float*)d_in[2];
    const float* wv = (const float*)d_in[3];
    const float* wo = (const float*)d_in[4];
    const float* cosb = (const float*)d_in[5];
    const float* sinb = (const float*)d_in[6];
    float* out = (float*)d_out;

    unsigned short* p = (unsigned short*)d_ws;
    unsigned short* xb = p;    p += (size_t)16777216;
    unsigned short* wqb = p;   p += (size_t)16777216;
    unsigned short* wob = p;   p += (size_t)16777216;
    unsigned short* qraw = p;  p += (size_t)16777216;
    unsigned short* qrope = p; p += (size_t)16777216;
    unsigned short* attn = p;  p += (size_t)16777216;
    unsigned short* wkb = p;   p += (size_t)4194304;
    unsigned short* wvb = p;   p += (size_t)4194304;
    unsigned short* kraw = p;  p += (size_t)4194304;
    unsigned short* vraw = p;  p += (size_t)4194304;
    unsigned short* krope = p; p += (size_t)4194304;
    unsigned short* vt = p;    p += (size_t)4194304;

    f2b_kernel<<<8192, 256, 0, stream>>>(x, xb, 2097152);
    f2b_kernel<<<8192, 256, 0, stream>>>(wq, wqb, 2097152);
    f2b_kernel<<<2048, 256, 0, stream>>>(wk, wkb, 524288);
    f2b_kernel<<<2048, 256, 0, stream>>>(wv, wvb, 524288);
    f2b_kernel<<<8192, 256, 0, stream>>>(wo, wob, 2097152);

    gemm_bt_kernel<unsigned short><<<1024, 256, 0, stream>>>(xb, wqb, qraw, 4096, 4096, 4096);
    gemm_bt_kernel<unsigned short><<<256, 256, 0, stream>>>(xb, wkb, kraw, 4096, 1024, 4096);
    gemm_bt_kernel<unsigned short><<<256, 256, 0, stream>>>(xb, wvb, vraw, 4096, 1024, 4096);

    rope_kernel<32><<<4096, 256, 0, stream>>>(qraw, cosb, sinb, qrope, 0.08838834764831845f);
    rope_kernel<8><<<1024, 256, 0, stream>>>(kraw, cosb, sinb, krope, 1.0f);
    vtrans_kernel<<<512, 256, 0, stream>>>(vraw, vt);

    attn_kernel<<<2048, 256, 0, stream>>>(qrope, krope, vt, attn);

    gemm_bt_kernel<float><<<1024, 256, 0, stream>>>(attn, wob, out, 4096, 4096, 4096);
}

// Round 2
// 940.146 us; speedup vs baseline: 1.1984x; 1.1984x over previous
//
#include <hip/hip_runtime.h>
#include <hip/hip_bf16.h>

#define B_ 2
#define S_ 2048
#define D_ 4096
#define H_ 32
#define KV_ 8
#define HD_ 128

typedef __attribute__((ext_vector_type(8))) short sh8;
typedef __attribute__((ext_vector_type(4))) float f32x4;

__device__ __forceinline__ float b2f(unsigned short u) {
    union { unsigned int i; float f; } v; v.i = ((unsigned)u) << 16; return v.f;
}
__device__ __forceinline__ unsigned short f2b(float f) {
    union { float f; unsigned int i; } v; v.f = f;
    unsigned r = v.i + 0x7fffu + ((v.i >> 16) & 1u);
    return (unsigned short)(r >> 16);
}
__device__ __forceinline__ void gload_lds16(const void* g, void* l) {
    __builtin_amdgcn_global_load_lds((const __attribute__((address_space(1))) void*)g,
                                     (__attribute__((address_space(3))) void*)l, 16, 0, 0);
}

#define BARX() do { asm volatile("" ::: "memory"); __builtin_amdgcn_s_barrier(); asm volatile("" ::: "memory"); } while (0)

// ---------------- fp32 -> bf16 convert ----------------
__global__ __launch_bounds__(256) void f2b_kernel(const float* __restrict__ in,
                                                  unsigned short* __restrict__ out, int n8) {
    int t = blockIdx.x * 256 + threadIdx.x;
    if (t >= n8) return;
    const float* p = in + (size_t)t * 8;
    float4 a = *(const float4*)p;
    float4 b = *(const float4*)(p + 4);
    sh8 o;
    o[0] = (short)f2b(a.x); o[1] = (short)f2b(a.y); o[2] = (short)f2b(a.z); o[3] = (short)f2b(a.w);
    o[4] = (short)f2b(b.x); o[5] = (short)f2b(b.y); o[6] = (short)f2b(b.z); o[7] = (short)f2b(b.w);
    *(sh8*)(out + (size_t)t * 8) = o;
}

__device__ __forceinline__ void cstore(float* C, size_t i, float v) { C[i] = v; }
__device__ __forceinline__ void cstore(unsigned short* C, size_t i, float v) { C[i] = f2b(v); }

// ---------------- 128^2 GEMM (m97 structure) — kept for K/V proj ----------------
template <typename CT>
__global__ __launch_bounds__(256) void gemm_bt_kernel(const unsigned short* __restrict__ A,
                                                      const unsigned short* __restrict__ Bm,
                                                      CT* __restrict__ C, int M, int N, int K) {
    __shared__ __align__(16) unsigned short As[128 * 32];
    __shared__ __align__(16) unsigned short Bs[128 * 32];
    int nwg = gridDim.x;
    int wg = blockIdx.x;
    int cpx = nwg >> 3;
    int swz = (wg & 7) * cpx + (wg >> 3);
    int nbn = N >> 7;
    int bm = swz / nbn, bn = swz % nbn;
    int t = threadIdx.x, w = t >> 6, l = t & 63;
    int wm = w >> 1, wn = w & 1;
    int fr = l & 15, fq = l >> 4;
    f32x4 acc[4][4];
#pragma unroll
    for (int i = 0; i < 4; i++)
#pragma unroll
        for (int j = 0; j < 4; j++) acc[i][j] = (f32x4){0.f, 0.f, 0.f, 0.f};
    const size_t rowA0 = (size_t)bm * 128, rowB0 = (size_t)bn * 128;
    int lrow = l >> 2;
    int lcb = (l & 3) * 16;
    for (int k0 = 0; k0 < K; k0 += 32) {
#pragma unroll
        for (int r = 0; r < 2; ++r) {
            int chunk = r * 4 + w;
            int row = chunk * 16 + lrow;
            const char* ga = (const char*)(A + (rowA0 + row) * (size_t)K + k0) + lcb;
            gload_lds16(ga, (char*)As + chunk * 1024);
            const char* gb = (const char*)(Bm + (rowB0 + row) * (size_t)K + k0) + lcb;
            gload_lds16(gb, (char*)Bs + chunk * 1024);
        }
        __syncthreads();
        sh8 af[4], bfv[4];
#pragma unroll
        for (int mi = 0; mi < 4; mi++) af[mi] = *(const sh8*)(As + (wm * 64 + mi * 16 + fr) * 32 + fq * 8);
#pragma unroll
        for (int ni = 0; ni < 4; ni++) bfv[ni] = *(const sh8*)(Bs + (wn * 64 + ni * 16 + fr) * 32 + fq * 8);
#pragma unroll
        for (int mi = 0; mi < 4; mi++)
#pragma unroll
            for (int ni = 0; ni < 4; ni++)
                acc[mi][ni] = __builtin_amdgcn_mfma_f32_16x16x32_bf16(af[mi], bfv[ni], acc[mi][ni], 0, 0, 0);
        __syncthreads();
    }
#pragma unroll
    for (int mi = 0; mi < 4; mi++)
#pragma unroll
        for (int ni = 0; ni < 4; ni++) {
            size_t row = rowA0 + wm * 64 + mi * 16 + fq * 4;
            size_t col = rowB0 + wn * 64 + ni * 16 + fr;
#pragma unroll
            for (int j = 0; j < 4; j++) cstore(C, (row + j) * (size_t)N + col, acc[mi][ni][j]);
        }
}

// ---------------- 256^2 8-phase GEMM (T1+T2+T3+T4+T5), C = A * B^T ----------------
// BM=BN=256, BK=64, 8 waves (2M x 4N), per-wave C = 128x64.
// LDS: per matrix 2 parities x 2 half-slabs of [128 rows][64 k] bf16.
//   A-slab mh holds global rows {mh*64..+63} u {128+mh*64..+63} (lr>=64 -> +128).
//   B-slab nh holds global cols {wn*64 + nh*32 + 0..31, wn=0..3} (lr = wn*32 + i).
// Quadrant order per tile: (m0,n0),(m0,n1),(m1,n1),(m1,n0) -> slab last reads:
//   A0:ph1  A1:ph3  B0:ph3  B1:ph2.
// Prefetch cadence (issue one half-slab per phase, first legal phase after slot death):
//   ph0: A1(t+1)->pn   ph1: B0(t+1)->pn   ph2: A0(t+2)->p   ph3: B1(t+2)->p
// FIFO at ph3's vmcnt(4): in-flight = {A0(t+2),B1(t+2)} (4 loads) => tile t+1 resident.
// T2 swizzle: 16B slot s' = s ^ (row&7); linear LDS dest, pre-swizzled global source.
#define MFMAQ(MH, NH)                                                                              \
    do {                                                                                           \
        __builtin_amdgcn_s_setprio(1);                                                             \
        _Pragma("unroll") for (int ks = 0; ks < 2; ks++)                                           \
        _Pragma("unroll") for (int mi = 0; mi < 4; mi++)                                           \
        _Pragma("unroll") for (int ni = 0; ni < 2; ni++)                                           \
            acc[(MH)*4 + mi][(NH)*2 + ni] = __builtin_amdgcn_mfma_f32_16x16x32_bf16(               \
                af[mi][ks], bfr[ni][ks], acc[(MH)*4 + mi][(NH)*2 + ni], 0, 0, 0);                  \
        __builtin_amdgcn_s_setprio(0);                                                             \
    } while (0)

__device__ __forceinline__ void stage2(const unsigned short* s, size_t off128, int tp,
                                       unsigned short* d) {
    const unsigned short* sp = s + (size_t)tp * 64;
    gload_lds16(sp, d);
    gload_lds16(sp + off128, d + 4096);
}

template <typename CT>
__global__ __launch_bounds__(512, 2) void gemm256_bt_kernel(const unsigned short* __restrict__ A,
                                                            const unsigned short* __restrict__ Bm,
                                                            CT* __restrict__ C, int M, int N, int K) {
    __shared__ __align__(16) unsigned short Al[2][2][8192];
    __shared__ __align__(16) unsigned short Bl[2][2][8192];
    const int NT = K >> 6;
    const int nwg = gridDim.x;
    const int wg = blockIdx.x;
    const int cpx = nwg >> 3;
    const int swz = (wg & 7) * cpx + (wg >> 3);
    const int nbn = N >> 8;
    const int bm = swz / nbn, bn = swz % nbn;
    const int T = threadIdx.x;
    const int w = T >> 6, l = T & 63;
    const int wm = w >> 2, wn = w & 3;
    const int fr = l & 15, fq = l >> 4;
    const int u = T >> 3;
    const int swc = ((T & 7) ^ (u & 7)) << 3;   // pre-swizzled source col (elements)
    const size_t Ks = (size_t)K;
    const size_t off128 = 128 * Ks;
    const unsigned short* a0s = A + ((size_t)bm * 256 + u) * Ks + swc;                      // A-slab mh0
    const unsigned short* a1s = A + ((size_t)bm * 256 + 64 + u) * Ks + swc;                 // A-slab mh1
    const unsigned short* b0s = Bm + ((size_t)bn * 256 + (u >> 5) * 64 + (u & 31)) * Ks + swc;  // B-slab nh0
    const unsigned short* b1s = b0s + 32 * Ks;                                              // B-slab nh1
    const int T8 = T * 8;
    int aoff[4][2], boff[2][2];
#pragma unroll
    for (int mi = 0; mi < 4; mi++)
#pragma unroll
        for (int ks = 0; ks < 2; ks++)
            aoff[mi][ks] = (wm * 64 + mi * 16 + fr) * 64 + ((((ks << 2) | fq) ^ (fr & 7)) << 3);
#pragma unroll
    for (int ni = 0; ni < 2; ni++)
#pragma unroll
        for (int ks = 0; ks < 2; ks++)
            boff[ni][ks] = (wn * 32 + ni * 16 + fr) * 64 + ((((ks << 2) | fq) ^ (fr & 7)) << 3);
    f32x4 acc[8][4];
#pragma unroll
    for (int i = 0; i < 8; i++)
#pragma unroll
        for (int j = 0; j < 4; j++) acc[i][j] = (f32x4){0.f, 0.f, 0.f, 0.f};

    // prologue: tile0 (par0) + steady-state tail {A0(1), B1(1)} (par1)
    stage2(a0s, off128, 0, &Al[0][0][T8]);
    stage2(a1s, off128, 0, &Al[0][1][T8]);
    stage2(b0s, off128, 0, &Bl[0][0][T8]);
    stage2(b1s, off128, 0, &Bl[0][1][T8]);
    const int t1c = (NT > 1) ? 1 : 0;
    stage2(a0s, off128, t1c, &Al[1][0][T8]);
    stage2(b1s, off128, t1c, &Bl[1][1][T8]);
    asm volatile("s_waitcnt vmcnt(4)" ::: "memory");
    BARX();

    sh8 af[4][2], bfr[2][2];
    for (int t = 0; t < NT; ++t) {
        const int p = t & 1, pn = p ^ 1;
        const int tp1 = (t + 1 < NT) ? t + 1 : NT - 1;
        const int tp2 = (t + 2 < NT) ? t + 2 : NT - 1;
        const unsigned short* Am0 = &Al[p][0][0];
        const unsigned short* Am1 = &Al[p][1][0];
        const unsigned short* Bn0 = &Bl[p][0][0];
        const unsigned short* Bn1 = &Bl[p][1][0];
        // ---- phase 0: quadrant (m0, n0) ----
#pragma unroll
        for (int mi = 0; mi < 4; mi++) {
            af[mi][0] = *(const sh8*)(Am0 + aoff[mi][0]);
            af[mi][1] = *(const sh8*)(Am0 + aoff[mi][1]);
        }
#pragma unroll
        for (int ni = 0; ni < 2; ni++) {
            bfr[ni][0] = *(const sh8*)(Bn0 + boff[ni][0]);
            bfr[ni][1] = *(const sh8*)(Bn0 + boff[ni][1]);
        }
        stage2(a1s, off128, tp1, &Al[pn][1][T8]);   // A1(t+1)
        BARX();
        MFMAQ(0, 0);
        BARX();
        // ---- phase 1: quadrant (m0, n1) ----
#pragma unroll
        for (int ni = 0; ni < 2; ni++) {
            bfr[ni][0] = *(const sh8*)(Bn1 + boff[ni][0]);
            bfr[ni][1] = *(const sh8*)(Bn1 + boff[ni][1]);
        }
        stage2(b0s, off128, tp1, &Bl[pn][0][T8]);   // B0(t+1)
        BARX();
        MFMAQ(0, 1);
        BARX();
        // ---- phase 2: quadrant (m1, n1) ----
#pragma unroll
        for (int mi = 0; mi < 4; mi++) {
            af[mi][0] = *(const sh8*)(Am1 + aoff[mi][0]);
            af[mi][1] = *(const sh8*)(Am1 + aoff[mi][1]);
        }
        stage2(a0s, off128, tp2, &Al[p][0][T8]);    // A0(t+2)
        BARX();
        MFMAQ(1, 1);
        BARX();
        // ---- phase 3: quadrant (m1, n0) ----
#pragma unroll
        for (int ni = 0; ni < 2; ni++) {
            bfr[ni][0] = *(const sh8*)(Bn0 + boff[ni][0]);
            bfr[ni][1] = *(const sh8*)(Bn0 + boff[ni][1]);
        }
        stage2(b1s, off128, tp2, &Bl[p][1][T8]);    // B1(t+2)
        asm volatile("s_waitcnt vmcnt(4)" ::: "memory");
        BARX();
        MFMAQ(1, 0);
        BARX();
    }
    // epilogue: C write
    const size_t crow0 = (size_t)bm * 256 + wm * 128;
    const size_t ccol0 = (size_t)bn * 256 + wn * 64;
#pragma unroll
    for (int mi8 = 0; mi8 < 8; mi8++)
#pragma unroll
        for (int ni4 = 0; ni4 < 4; ni4++) {
            size_t r = crow0 + mi8 * 16 + fq * 4;
            size_t c = ccol0 + ni4 * 16 + fr;
#pragma unroll
            for (int j = 0; j < 4; j++) cstore(C, (r + j) * (size_t)N + c, acc[mi8][ni4][j]);
        }
}

// ---------------- RoPE (+ optional 1/sqrt(HD) fold) ----------------
template <int NH>
__global__ __launch_bounds__(256) void rope_kernel(const unsigned short* __restrict__ raw,
                                                   const float* __restrict__ cosb,
                                                   const float* __restrict__ sinb,
                                                   unsigned short* __restrict__ out, float scale) {
    int t = blockIdx.x * 256 + threadIdx.x;
    int g = t & 7;
    int h = (t >> 3) & (NH - 1);
    int row = t / (8 * NH);
    if (row >= B_ * S_) return;
    int b = row >> 11, s = row & (S_ - 1);
    const unsigned short* qr = raw + (size_t)row * (NH * HD_) + h * HD_ + g * 8;
    sh8 lo = *(const sh8*)qr;
    sh8 hi = *(const sh8*)(qr + 64);
    const float* cp = cosb + (size_t)row * HD_ + g * 8;
    const float* sp = sinb + (size_t)row * HD_ + g * 8;
    float4 c0 = *(const float4*)cp, c1 = *(const float4*)(cp + 4);
    float4 s0 = *(const float4*)sp, s1 = *(const float4*)(sp + 4);
    float cc[8] = {c0.x, c0.y, c0.z, c0.w, c1.x, c1.y, c1.z, c1.w};
    float ss[8] = {s0.x, s0.y, s0.z, s0.w, s1.x, s1.y, s1.z, s1.w};
    sh8 olo, ohi;
#pragma unroll
    for (int i = 0; i < 8; i++) {
        float fl = b2f((unsigned short)lo[i]);
        float fh = b2f((unsigned short)hi[i]);
        olo[i] = (short)f2b((fl * cc[i] - fh * ss[i]) * scale);
        ohi[i] = (short)f2b((fh * cc[i] + fl * ss[i]) * scale);
    }
    unsigned short* op = out + (((size_t)b * NH + h) * S_ + s) * HD_ + g * 8;
    *(sh8*)op = olo;
    *(sh8*)(op + 64) = ohi;
}

// ---------------- V transpose: (B*S, KV*HD) -> (B, KV, HD, S) ----------------
__global__ __launch_bounds__(256) void vtrans_kernel(const unsigned short* __restrict__ vraw,
                                                     unsigned short* __restrict__ vt) {
    __shared__ unsigned short tile[64][132];
    int bid = blockIdx.x;
    int st = bid & 31;
    int kv = (bid >> 5) & 7;
    int b = bid >> 8;
    int s0 = st * 64;
    int t = threadIdx.x;
    {
        int s = t >> 2, dq = (t & 3) * 32;
        const unsigned short* src = vraw + ((size_t)(b * S_ + s0 + s)) * (KV_ * HD_) + kv * HD_ + dq;
#pragma unroll
        for (int i = 0; i < 4; i++) *(sh8*)&tile[s][dq + i * 8] = *(const sh8*)(src + i * 8);
    }
    __syncthreads();
    {
        int d = t & 127, sh = t >> 7;
        unsigned short* dst = vt + (((size_t)(b * KV_ + kv)) * HD_ + d) * S_ + s0 + sh * 32;
#pragma unroll
        for (int q = 0; q < 4; q++) {
            sh8 vv;
#pragma unroll
            for (int e = 0; e < 8; e++) vv[e] = (short)tile[sh * 32 + q * 8 + e][d];
            *(sh8*)(dst + q * 8) = vv;
        }
    }
}

// ---------------- causal GQA flash attention ----------------
__global__ __launch_bounds__(256) void attn_kernel(const unsigned short* __restrict__ Q,
                                                   const unsigned short* __restrict__ Kr,
                                                   const unsigned short* __restrict__ Vt,
                                                   unsigned short* __restrict__ O) {
    __shared__ __align__(16) unsigned short Kl[64 * 128];
    __shared__ __align__(16) unsigned short Vl[128 * 64];
    __shared__ __align__(16) unsigned short Pl[4][16 * 72];
    int nwg = gridDim.x;
    int bid0 = blockIdx.x;
    int cpx = nwg >> 3;
    int u = (bid0 & 7) * cpx + (bid0 >> 3);
    int qi = u & 31;
    int h = (u >> 5) & 31;
    int b = u >> 10;
    int kv = h >> 2;
    int t = threadIdx.x, w = t >> 6, l = t & 63;
    int fr = l & 15, fq = l >> 4;
    int qw = qi * 64 + w * 16;
    const unsigned short* Qp = Q + (((size_t)b * H_ + h) * S_ + qw + fr) * HD_;
    sh8 qf[4];
#pragma unroll
    for (int kk = 0; kk < 4; kk++) qf[kk] = *(const sh8*)(Qp + kk * 32 + fq * 8);
    const unsigned short* Kg = Kr + ((size_t)b * KV_ + kv) * S_ * HD_;
    const unsigned short* Vg = Vt + ((size_t)b * KV_ + kv) * HD_ * S_;
    f32x4 po[8];
#pragma unroll
    for (int i = 0; i < 8; i++) po[i] = (f32x4){0.f, 0.f, 0.f, 0.f};
    float m_r[4] = {-3.0e38f, -3.0e38f, -3.0e38f, -3.0e38f};
    float l_r[4] = {0.f, 0.f, 0.f, 0.f};
    for (int j = 0; j <= qi; ++j) {
#pragma unroll
        for (int r = 0; r < 4; ++r) {
            int chunk = r * 4 + w;
            {
                int lb = chunk * 1024 + l * 16;
                int srow = lb >> 8;
                int cs = (lb >> 4) & 15;
                int gs = cs ^ (srow & 7);
                const char* ga = (const char*)(Kg + (size_t)(j * 64 + srow) * HD_) + gs * 16;
                gload_lds16(ga, (char*)Kl + chunk * 1024);
            }
            {
                int lb = chunk * 1024 + l * 16;
                int drow = lb >> 7;
                int cs = (lb >> 4) & 7;
                int gs = cs ^ (drow & 7);
                const char* gv = (const char*)(Vg + (size_t)drow * S_ + j * 64 + gs * 8);
                gload_lds16(gv, (char*)Vl + chunk * 1024);
            }
        }
        __syncthreads();
        f32x4 sacc[4];
#pragma unroll
        for (int nc = 0; nc < 4; nc++) {
            sacc[nc] = (f32x4){0.f, 0.f, 0.f, 0.f};
            int n = nc * 16 + fr;
#pragma unroll
            for (int kk = 0; kk < 4; kk++) {
                sh8 kf = *(const sh8*)(Kl + n * 128 + (((kk * 4 + fq) ^ (n & 7)) * 8));
                sacc[nc] = __builtin_amdgcn_mfma_f32_16x16x32_bf16(qf[kk], kf, sacc[nc], 0, 0, 0);
            }
        }
        if (j == qi) {
#pragma unroll
            for (int nc = 0; nc < 4; nc++) {
                int kg = j * 64 + nc * 16 + fr;
#pragma unroll
                for (int j3 = 0; j3 < 4; j3++) {
                    int qg = qw + fq * 4 + j3;
                    if (kg > qg) sacc[nc][j3] = -1e30f;
                }
            }
        }
        float pb[4][4];
#pragma unroll
        for (int j3 = 0; j3 < 4; j3++) {
            float tm = sacc[0][j3];
#pragma unroll
            for (int nc = 1; nc < 4; nc++) tm = fmaxf(tm, sacc[nc][j3]);
            tm = fmaxf(tm, __shfl_xor(tm, 1));
            tm = fmaxf(tm, __shfl_xor(tm, 2));
            tm = fmaxf(tm, __shfl_xor(tm, 4));
            tm = fmaxf(tm, __shfl_xor(tm, 8));
            float newm = fmaxf(m_r[j3], tm);
            float alpha = __expf(m_r[j3] - newm);
            float rs = 0.f;
#pragma unroll
            for (int nc = 0; nc < 4; nc++) {
                float p = __expf(sacc[nc][j3] - newm);
                pb[nc][j3] = p;
                rs += p;
            }
            rs += __shfl_xor(rs, 1);
            rs += __shfl_xor(rs, 2);
            rs += __shfl_xor(rs, 4);
            rs += __shfl_xor(rs, 8);
            l_r[j3] = l_r[j3] * alpha + rs;
            m_r[j3] = newm;
#pragma unroll
            for (int dc = 0; dc < 8; dc++) po[dc][j3] *= alpha;
        }
        unsigned short* Pw = Pl[w];
#pragma unroll
        for (int nc = 0; nc < 4; nc++)
#pragma unroll
            for (int j3 = 0; j3 < 4; j3++)
                Pw[(fq * 4 + j3) * 72 + nc * 16 + fr] = f2b(pb[nc][j3]);
#pragma unroll
        for (int kc = 0; kc < 2; kc++) {
            sh8 pf = *(const sh8*)(Pw + fr * 72 + kc * 32 + fq * 8);
#pragma unroll
            for (int dc = 0; dc < 8; dc++) {
                int d = dc * 16 + fr;
                sh8 vf = *(const sh8*)(Vl + d * 64 + (((kc * 4 + fq) ^ (d & 7)) * 8));
                po[dc] = __builtin_amdgcn_mfma_f32_16x16x32_bf16(pf, vf, po[dc], 0, 0, 0);
            }
        }
        __syncthreads();
    }
#pragma unroll
    for (int j3 = 0; j3 < 4; j3++) {
        float inv = 1.f / l_r[j3];
        size_t orow = (size_t)b * S_ + qw + fq * 4 + j3;
#pragma unroll
        for (int dc = 0; dc < 8; dc++)
            O[orow * (H_ * HD_) + h * HD_ + dc * 16 + fr] = f2b(po[dc][j3] * inv);
    }
}

// ---------------- host launcher ----------------
extern "C" void kernel_launch(void* const* d_in, const int* in_sizes, int n_in,
                              void* d_out, int out_size, void* d_ws, size_t ws_size,
                              hipStream_t stream) {
    const float* x = (const float*)d_in[0];
    const float* wq = (const float*)d_in[1];
    const float* wk = (const float*)d_in[2];
    const float* wv = (const float*)d_in[3];
    const float* wo = (const float*)d_in[4];
    const float* cosb = (const float*)d_in[5];
    const float* sinb = (const float*)d_in[6];
    float* out = (float*)d_out;

    unsigned short* p = (unsigned short*)d_ws;
    unsigned short* xb = p;    p += (size_t)16777216;
    unsigned short* wqb = p;   p += (size_t)16777216;
    unsigned short* wob = p;   p += (size_t)16777216;
    unsigned short* qraw = p;  p += (size_t)16777216;
    unsigned short* qrope = p; p += (size_t)16777216;
    unsigned short* attn = p;  p += (size_t)16777216;
    unsigned short* wkb = p;   p += (size_t)4194304;
    unsigned short* wvb = p;   p += (size_t)4194304;
    unsigned short* kraw = p;  p += (size_t)4194304;
    unsigned short* vraw = p;  p += (size_t)4194304;
    unsigned short* krope = p; p += (size_t)4194304;
    unsigned short* vt = p;    p += (size_t)4194304;

    f2b_kernel<<<8192, 256, 0, stream>>>(x, xb, 2097152);
    f2b_kernel<<<8192, 256, 0, stream>>>(wq, wqb, 2097152);
    f2b_kernel<<<2048, 256, 0, stream>>>(wk, wkb, 524288);
    f2b_kernel<<<2048, 256, 0, stream>>>(wv, wvb, 524288);
    f2b_kernel<<<8192, 256, 0, stream>>>(wo, wob, 2097152);

    gemm256_bt_kernel<unsigned short><<<256, 512, 0, stream>>>(xb, wqb, qraw, 4096, 4096, 4096);
    gemm_bt_kernel<unsigned short><<<256, 256, 0, stream>>>(xb, wkb, kraw, 4096, 1024, 4096);
    gemm_bt_kernel<unsigned short><<<256, 256, 0, stream>>>(xb, wvb, vraw, 4096, 1024, 4096);

    rope_kernel<32><<<4096, 256, 0, stream>>>(qraw, cosb, sinb, qrope, 0.08838834764831845f);
    rope_kernel<8><<<1024, 256, 0, stream>>>(kraw, cosb, sinb, krope, 1.0f);
    vtrans_kernel<<<512, 256, 0, stream>>>(vraw, vt);

    attn_kernel<<<2048, 256, 0, stream>>>(qrope, krope, vt, attn);

    gemm256_bt_kernel<float><<<256, 512, 0, stream>>>(attn, wob, out, 4096, 4096, 4096);
}

// Round 3
// 827.437 us; speedup vs baseline: 1.3617x; 1.1362x over previous
//
#include <hip/hip_runtime.h>
#include <hip/hip_bf16.h>

#define B_ 2
#define S_ 2048
#define D_ 4096
#define H_ 32
#define KV_ 8
#define HD_ 128

typedef __attribute__((ext_vector_type(8))) short sh8;
typedef __attribute__((ext_vector_type(4))) short sh4;
typedef __attribute__((ext_vector_type(4))) float f32x4;

__device__ __forceinline__ float b2f(unsigned short u) {
    union { unsigned int i; float f; } v; v.i = ((unsigned)u) << 16; return v.f;
}
__device__ __forceinline__ unsigned short f2b(float f) {
    union { float f; unsigned int i; } v; v.f = f;
    unsigned r = v.i + 0x7fffu + ((v.i >> 16) & 1u);
    return (unsigned short)(r >> 16);
}
__device__ __forceinline__ void gload_lds16(const void* g, void* l) {
    __builtin_amdgcn_global_load_lds((const __attribute__((address_space(1))) void*)g,
                                     (__attribute__((address_space(3))) void*)l, 16, 0, 0);
}

#define BARX() do { asm volatile("" ::: "memory"); __builtin_amdgcn_s_barrier(); asm volatile("" ::: "memory"); } while (0)

// ---------------- fp32 -> bf16 convert ----------------
__global__ __launch_bounds__(256) void f2b_kernel(const float* __restrict__ in,
                                                  unsigned short* __restrict__ out, int n8) {
    int t = blockIdx.x * 256 + threadIdx.x;
    if (t >= n8) return;
    const float* p = in + (size_t)t * 8;
    float4 a = *(const float4*)p;
    float4 b = *(const float4*)(p + 4);
    sh8 o;
    o[0] = (short)f2b(a.x); o[1] = (short)f2b(a.y); o[2] = (short)f2b(a.z); o[3] = (short)f2b(a.w);
    o[4] = (short)f2b(b.x); o[5] = (short)f2b(b.y); o[6] = (short)f2b(b.z); o[7] = (short)f2b(b.w);
    *(sh8*)(out + (size_t)t * 8) = o;
}

__device__ __forceinline__ void cstore(float* C, size_t i, float v) { C[i] = v; }
__device__ __forceinline__ void cstore(unsigned short* C, size_t i, float v) { C[i] = f2b(v); }

// ---------------- 256^2 8-phase GEMM (T1+T2+T3+T4+T5), C = A * B^T ----------------
#define MFMAQ(MH, NH)                                                                              \
    do {                                                                                           \
        __builtin_amdgcn_s_setprio(1);                                                             \
        _Pragma("unroll") for (int ks = 0; ks < 2; ks++)                                           \
        _Pragma("unroll") for (int mi = 0; mi < 4; mi++)                                           \
        _Pragma("unroll") for (int ni = 0; ni < 2; ni++)                                           \
            acc[(MH)*4 + mi][(NH)*2 + ni] = __builtin_amdgcn_mfma_f32_16x16x32_bf16(               \
                af[mi][ks], bfr[ni][ks], acc[(MH)*4 + mi][(NH)*2 + ni], 0, 0, 0);                  \
        __builtin_amdgcn_s_setprio(0);                                                             \
    } while (0)

__device__ __forceinline__ void stage2(const unsigned short* s, size_t off128, int tp,
                                       unsigned short* d) {
    const unsigned short* sp = s + (size_t)tp * 64;
    gload_lds16(sp, d);
    gload_lds16(sp + off128, d + 4096);
}

template <typename CT>
__global__ __launch_bounds__(512, 2) void gemm256_bt_kernel(const unsigned short* __restrict__ A,
                                                            const unsigned short* __restrict__ Bm,
                                                            CT* __restrict__ C, int M, int N, int K) {
    __shared__ __align__(16) unsigned short Al[2][2][8192];
    __shared__ __align__(16) unsigned short Bl[2][2][8192];
    const int NT = K >> 6;
    const int nwg = gridDim.x;
    const int wg = blockIdx.x;
    const int cpx = nwg >> 3;
    const int swz = (wg & 7) * cpx + (wg >> 3);
    const int nbn = N >> 8;
    const int bm = swz / nbn, bn = swz % nbn;
    const int T = threadIdx.x;
    const int w = T >> 6, l = T & 63;
    const int wm = w >> 2, wn = w & 3;
    const int fr = l & 15, fq = l >> 4;
    const int u = T >> 3;
    const int swc = ((T & 7) ^ (u & 7)) << 3;
    const size_t Ks = (size_t)K;
    const size_t off128 = 128 * Ks;
    const unsigned short* a0s = A + ((size_t)bm * 256 + u) * Ks + swc;
    const unsigned short* a1s = A + ((size_t)bm * 256 + 64 + u) * Ks + swc;
    const unsigned short* b0s = Bm + ((size_t)bn * 256 + (u >> 5) * 64 + (u & 31)) * Ks + swc;
    const unsigned short* b1s = b0s + 32 * Ks;
    const int T8 = T * 8;
    int aoff[4][2], boff[2][2];
#pragma unroll
    for (int mi = 0; mi < 4; mi++)
#pragma unroll
        for (int ks = 0; ks < 2; ks++)
            aoff[mi][ks] = (wm * 64 + mi * 16 + fr) * 64 + ((((ks << 2) | fq) ^ (fr & 7)) << 3);
#pragma unroll
    for (int ni = 0; ni < 2; ni++)
#pragma unroll
        for (int ks = 0; ks < 2; ks++)
            boff[ni][ks] = (wn * 32 + ni * 16 + fr) * 64 + ((((ks << 2) | fq) ^ (fr & 7)) << 3);
    f32x4 acc[8][4];
#pragma unroll
    for (int i = 0; i < 8; i++)
#pragma unroll
        for (int j = 0; j < 4; j++) acc[i][j] = (f32x4){0.f, 0.f, 0.f, 0.f};

    stage2(a0s, off128, 0, &Al[0][0][T8]);
    stage2(a1s, off128, 0, &Al[0][1][T8]);
    stage2(b0s, off128, 0, &Bl[0][0][T8]);
    stage2(b1s, off128, 0, &Bl[0][1][T8]);
    const int t1c = (NT > 1) ? 1 : 0;
    stage2(a0s, off128, t1c, &Al[1][0][T8]);
    stage2(b1s, off128, t1c, &Bl[1][1][T8]);
    asm volatile("s_waitcnt vmcnt(4)" ::: "memory");
    BARX();

    sh8 af[4][2], bfr[2][2];
    for (int t = 0; t < NT; ++t) {
        const int p = t & 1, pn = p ^ 1;
        const int tp1 = (t + 1 < NT) ? t + 1 : NT - 1;
        const int tp2 = (t + 2 < NT) ? t + 2 : NT - 1;
        const unsigned short* Am0 = &Al[p][0][0];
        const unsigned short* Am1 = &Al[p][1][0];
        const unsigned short* Bn0 = &Bl[p][0][0];
        const unsigned short* Bn1 = &Bl[p][1][0];
#pragma unroll
        for (int mi = 0; mi < 4; mi++) {
            af[mi][0] = *(const sh8*)(Am0 + aoff[mi][0]);
            af[mi][1] = *(const sh8*)(Am0 + aoff[mi][1]);
        }
#pragma unroll
        for (int ni = 0; ni < 2; ni++) {
            bfr[ni][0] = *(const sh8*)(Bn0 + boff[ni][0]);
            bfr[ni][1] = *(const sh8*)(Bn0 + boff[ni][1]);
        }
        stage2(a1s, off128, tp1, &Al[pn][1][T8]);
        BARX();
        MFMAQ(0, 0);
        BARX();
#pragma unroll
        for (int ni = 0; ni < 2; ni++) {
            bfr[ni][0] = *(const sh8*)(Bn1 + boff[ni][0]);
            bfr[ni][1] = *(const sh8*)(Bn1 + boff[ni][1]);
        }
        stage2(b0s, off128, tp1, &Bl[pn][0][T8]);
        BARX();
        MFMAQ(0, 1);
        BARX();
#pragma unroll
        for (int mi = 0; mi < 4; mi++) {
            af[mi][0] = *(const sh8*)(Am1 + aoff[mi][0]);
            af[mi][1] = *(const sh8*)(Am1 + aoff[mi][1]);
        }
        stage2(a0s, off128, tp2, &Al[p][0][T8]);
        BARX();
        MFMAQ(1, 1);
        BARX();
#pragma unroll
        for (int ni = 0; ni < 2; ni++) {
            bfr[ni][0] = *(const sh8*)(Bn0 + boff[ni][0]);
            bfr[ni][1] = *(const sh8*)(Bn0 + boff[ni][1]);
        }
        stage2(b1s, off128, tp2, &Bl[p][1][T8]);
        asm volatile("s_waitcnt vmcnt(4)" ::: "memory");
        BARX();
        MFMAQ(1, 0);
        BARX();
    }
    const size_t crow0 = (size_t)bm * 256 + wm * 128;
    const size_t ccol0 = (size_t)bn * 256 + wn * 64;
#pragma unroll
    for (int mi8 = 0; mi8 < 8; mi8++)
#pragma unroll
        for (int ni4 = 0; ni4 < 4; ni4++) {
            size_t r = crow0 + mi8 * 16 + fq * 4;
            size_t c = ccol0 + ni4 * 16 + fr;
#pragma unroll
            for (int j = 0; j < 4; j++) cstore(C, (r + j) * (size_t)N + c, acc[mi8][ni4][j]);
        }
}

// ---------------- RoPE from fused QKV buffer ----------------
template <int NH>
__global__ __launch_bounds__(256) void rope_kernel(const unsigned short* __restrict__ raw,
                                                   const float* __restrict__ cosb,
                                                   const float* __restrict__ sinb,
                                                   unsigned short* __restrict__ out, float scale,
                                                   int srcOff, int srcStride) {
    int t = blockIdx.x * 256 + threadIdx.x;
    int g = t & 7;
    int h = (t >> 3) & (NH - 1);
    int row = t / (8 * NH);
    if (row >= B_ * S_) return;
    int b = row >> 11, s = row & (S_ - 1);
    const unsigned short* qr = raw + (size_t)row * srcStride + srcOff + h * HD_ + g * 8;
    sh8 lo = *(const sh8*)qr;
    sh8 hi = *(const sh8*)(qr + 64);
    const float* cp = cosb + (size_t)row * HD_ + g * 8;
    const float* sp = sinb + (size_t)row * HD_ + g * 8;
    float4 c0 = *(const float4*)cp, c1 = *(const float4*)(cp + 4);
    float4 s0 = *(const float4*)sp, s1 = *(const float4*)(sp + 4);
    float cc[8] = {c0.x, c0.y, c0.z, c0.w, c1.x, c1.y, c1.z, c1.w};
    float ss[8] = {s0.x, s0.y, s0.z, s0.w, s1.x, s1.y, s1.z, s1.w};
    sh8 olo, ohi;
#pragma unroll
    for (int i = 0; i < 8; i++) {
        float fl = b2f((unsigned short)lo[i]);
        float fh = b2f((unsigned short)hi[i]);
        olo[i] = (short)f2b((fl * cc[i] - fh * ss[i]) * scale);
        ohi[i] = (short)f2b((fh * cc[i] + fl * ss[i]) * scale);
    }
    unsigned short* op = out + (((size_t)b * NH + h) * S_ + s) * HD_ + g * 8;
    *(sh8*)op = olo;
    *(sh8*)(op + 64) = ohi;
}

// ---------------- V transpose: qkvraw V-section -> (B, KV, HD, S) ----------------
__global__ __launch_bounds__(256) void vtrans_kernel(const unsigned short* __restrict__ vraw,
                                                     unsigned short* __restrict__ vt) {
    __shared__ unsigned short tile[64][132];
    int bid = blockIdx.x;
    int st = bid & 31;
    int kv = (bid >> 5) & 7;
    int b = bid >> 8;
    int s0 = st * 64;
    int t = threadIdx.x;
    {
        int s = t >> 2, dq = (t & 3) * 32;
        const unsigned short* src = vraw + ((size_t)(b * S_ + s0 + s)) * 6144 + 5120 + kv * HD_ + dq;
#pragma unroll
        for (int i = 0; i < 4; i++) *(sh8*)&tile[s][dq + i * 8] = *(const sh8*)(src + i * 8);
    }
    __syncthreads();
    {
        int d = t & 127, sh = t >> 7;
        unsigned short* dst = vt + (((size_t)(b * KV_ + kv)) * HD_ + d) * S_ + s0 + sh * 32;
#pragma unroll
        for (int q = 0; q < 4; q++) {
            sh8 vv;
#pragma unroll
            for (int e = 0; e < 8; e++) vv[e] = (short)tile[sh * 32 + q * 8 + e][d];
            *(sh8*)(dst + q * 8) = vv;
        }
    }
}

// ---------------- PV mfma: 16x16x16 bf16 (K=16), A-frag = in-register P ----------------
#if __has_builtin(__builtin_amdgcn_mfma_f32_16x16x16bf16_1k)
__device__ __forceinline__ f32x4 pv_mfma(sh4 a, sh4 b, f32x4 c) {
    return __builtin_amdgcn_mfma_f32_16x16x16bf16_1k(a, b, c, 0, 0, 0);
}
#else
__device__ __forceinline__ f32x4 pv_mfma(sh4 a, sh4 b, f32x4 c) {
    sh8 a8 = {a[0], a[1], a[2], a[3], 0, 0, 0, 0};
    sh8 b8 = {b[0], b[1], b[2], b[3], 0, 0, 0, 0};
    return __builtin_amdgcn_mfma_f32_16x16x32_bf16(a8, b8, c, 0, 0, 0);
}
#endif

// ---------------- causal GQA flash attention (swapped QK^T, in-register softmax) ----------------
// Q: (B,H,S,HD) bf16 pre-scaled; Kr: (B,KV,S,HD); Vt: (B,KV,HD,S); O: (B,S,H*HD)
// Swapped S^T: sacc[nc] lane l holds S[k=j*64+nc*16+fq*4+reg][q=qw+fr] -> one q-row per lane.
// P layout == A-frag of mfma_16x16x16_bf16 exactly: no cross-lane redistribution needed.
__global__ __launch_bounds__(256, 4) void attn_kernel(const unsigned short* __restrict__ Q,
                                                      const unsigned short* __restrict__ Kr,
                                                      const unsigned short* __restrict__ Vt,
                                                      unsigned short* __restrict__ O) {
    __shared__ __align__(16) unsigned short Kl[64 * 128];  // [s][d] source-swizzled
    __shared__ __align__(16) unsigned short Vl[128 * 64];  // [d][s] source-swizzled
    int nwg = gridDim.x;
    int bid0 = blockIdx.x;
    int cpx = nwg >> 3;
    int u = (bid0 & 7) * cpx + (bid0 >> 3);
    int qi = u & 31;
    int h = (u >> 5) & 31;
    int b = u >> 10;
    int kv = h >> 2;
    int t = threadIdx.x, w = t >> 6, l = t & 63;
    int fr = l & 15, fq = l >> 4;
    int qw = qi * 64 + w * 16;
    const unsigned short* Qp = Q + (((size_t)b * H_ + h) * S_ + qw + fr) * HD_;
    sh8 qf[4];
#pragma unroll
    for (int kk = 0; kk < 4; kk++) qf[kk] = *(const sh8*)(Qp + kk * 32 + fq * 8);
    const unsigned short* Kg = Kr + ((size_t)b * KV_ + kv) * S_ * HD_;
    const unsigned short* Vg = Vt + ((size_t)b * KV_ + kv) * HD_ * S_;
    f32x4 po[8];
#pragma unroll
    for (int i = 0; i < 8; i++) po[i] = (f32x4){0.f, 0.f, 0.f, 0.f};
    float m_r = -3.0e38f;
    float l_r = 0.f;
    for (int j = 0; j <= qi; ++j) {
#pragma unroll
        for (int r = 0; r < 4; ++r) {
            int chunk = r * 4 + w;
            {   // K tile: LDS slot (s, c') <- global slot (s, c'^(s&7))
                int lb = chunk * 1024 + l * 16;
                int srow = lb >> 8;
                int cs = (lb >> 4) & 15;
                int gs = cs ^ (srow & 7);
                const char* ga = (const char*)(Kg + (size_t)(j * 64 + srow) * HD_) + gs * 16;
                gload_lds16(ga, (char*)Kl + chunk * 1024);
            }
            {   // V tile: LDS slot (d, c') <- global slot (d, c'^(d&7))
                int lb = chunk * 1024 + l * 16;
                int drow = lb >> 7;
                int cs = (lb >> 4) & 7;
                int gs = cs ^ (drow & 7);
                const char* gv = (const char*)(Vg + (size_t)drow * S_ + j * 64 + gs * 8);
                gload_lds16(gv, (char*)Vl + chunk * 1024);
            }
        }
        __syncthreads();
        // S^T = K Q^T : sacc[nc] rows = k (nc*16 + fq*4 + reg), col = q (fr)
        f32x4 sacc[4];
#pragma unroll
        for (int nc = 0; nc < 4; nc++) {
            sacc[nc] = (f32x4){0.f, 0.f, 0.f, 0.f};
            int n = nc * 16 + fr;
#pragma unroll
            for (int kk = 0; kk < 4; kk++) {
                sh8 kf = *(const sh8*)(Kl + n * 128 + (((kk * 4 + fq) ^ (n & 7)) * 8));
                sacc[nc] = __builtin_amdgcn_mfma_f32_16x16x32_bf16(kf, qf[kk], sacc[nc], 0, 0, 0);
            }
        }
        if (j == qi) {
            int qg = qw + fr;
#pragma unroll
            for (int nc = 0; nc < 4; nc++)
#pragma unroll
                for (int j3 = 0; j3 < 4; j3++) {
                    int kg = j * 64 + nc * 16 + fq * 4 + j3;
                    if (kg > qg) sacc[nc][j3] = -1e30f;
                }
        }
        // per-lane q-row softmax (reduce over fq groups: xor16 + xor32)
        float tm = sacc[0][0];
#pragma unroll
        for (int nc = 0; nc < 4; nc++)
#pragma unroll
            for (int j3 = 0; j3 < 4; j3++) tm = fmaxf(tm, sacc[nc][j3]);
        tm = fmaxf(tm, __shfl_xor(tm, 16));
        tm = fmaxf(tm, __shfl_xor(tm, 32));
        bool resc = !__all(tm <= m_r + 8.0f);   // defer-max (T13), wave-uniform
        if (resc) {
            float nm = fmaxf(m_r, tm);
            float alpha = __expf(m_r - nm);
            m_r = nm;
            l_r *= alpha;
            float aj[4];
#pragma unroll
            for (int j3 = 0; j3 < 4; j3++) aj[j3] = __shfl(alpha, (l & 48) | (fq * 4 + j3));
#pragma unroll
            for (int dc = 0; dc < 8; dc++)
#pragma unroll
                for (int j3 = 0; j3 < 4; j3++) po[dc][j3] *= aj[j3];
        }
        float rs = 0.f;
#pragma unroll
        for (int nc = 0; nc < 4; nc++)
#pragma unroll
            for (int j3 = 0; j3 < 4; j3++) {
                float pv = __expf(sacc[nc][j3] - m_r);
                sacc[nc][j3] = pv;
                rs += pv;
            }
        rs += __shfl_xor(rs, 16);
        rs += __shfl_xor(rs, 32);
        l_r += rs;
        // pack P -> bf16 A-frags (layout already matches 16x16x16 A operand)
        sh4 pa[4];
#pragma unroll
        for (int nc = 0; nc < 4; nc++) {
            unsigned int lo, hi;
            asm("v_cvt_pk_bf16_f32 %0, %1, %2" : "=v"(lo) : "v"(sacc[nc][0]), "v"(sacc[nc][1]));
            asm("v_cvt_pk_bf16_f32 %0, %1, %2" : "=v"(hi) : "v"(sacc[nc][2]), "v"(sacc[nc][3]));
            union { unsigned int u2[2]; sh4 v; } pk;
            pk.u2[0] = lo; pk.u2[1] = hi;
            pa[nc] = pk.v;
        }
        // PV: po[dc] (rows=q(fq*4+reg), col=d(fr)) += P(16q x 64k) * V(64k x 16d)
#pragma unroll
        for (int dc = 0; dc < 8; dc++) {
            int d = dc * 16 + fr;
#pragma unroll
            for (int nc = 0; nc < 4; nc++) {
                const unsigned short* vp =
                    Vl + d * 64 + (((2 * nc + (fq >> 1)) ^ (d & 7)) * 8) + (fq & 1) * 4;
                sh4 vf = *(const sh4*)vp;
                po[dc] = pv_mfma(pa[nc], vf, po[dc]);
            }
        }
        __syncthreads();
    }
    float il = 1.f / l_r;
    float inj[4];
#pragma unroll
    for (int j3 = 0; j3 < 4; j3++) inj[j3] = __shfl(il, (l & 48) | (fq * 4 + j3));
#pragma unroll
    for (int j3 = 0; j3 < 4; j3++) {
        size_t orow = (size_t)b * S_ + qw + fq * 4 + j3;
#pragma unroll
        for (int dc = 0; dc < 8; dc++)
            O[orow * (H_ * HD_) + h * HD_ + dc * 16 + fr] = f2b(po[dc][j3] * inj[j3]);
    }
}

// ---------------- host launcher ----------------
extern "C" void kernel_launch(void* const* d_in, const int* in_sizes, int n_in,
                              void* d_out, int out_size, void* d_ws, size_t ws_size,
                              hipStream_t stream) {
    const float* x = (const float*)d_in[0];
    const float* wq = (const float*)d_in[1];
    const float* wk = (const float*)d_in[2];
    const float* wv = (const float*)d_in[3];
    const float* wo = (const float*)d_in[4];
    const float* cosb = (const float*)d_in[5];
    const float* sinb = (const float*)d_in[6];
    float* out = (float*)d_out;

    unsigned short* p = (unsigned short*)d_ws;
    unsigned short* xb = p;      p += (size_t)16777216;   // 4096 x 4096
    unsigned short* wqkvb = p;   p += (size_t)25165824;   // 6144 x 4096  (wq|wk|wv rows)
    unsigned short* wob = p;     p += (size_t)16777216;   // 4096 x 4096
    unsigned short* qkvraw = p;  p += (size_t)25165824;   // 4096 x 6144
    unsigned short* qrope = p;   p += (size_t)16777216;   // (B,H,S,HD)
    unsigned short* krope = p;   p += (size_t)4194304;    // (B,KV,S,HD)
    unsigned short* vt = p;      p += (size_t)4194304;    // (B,KV,HD,S)
    unsigned short* attnb = p;   p += (size_t)16777216;   // (B,S,H*HD)

    f2b_kernel<<<8192, 256, 0, stream>>>(x, xb, 2097152);
    f2b_kernel<<<8192, 256, 0, stream>>>(wq, wqkvb, 2097152);
    f2b_kernel<<<2048, 256, 0, stream>>>(wk, wqkvb + (size_t)16777216, 524288);
    f2b_kernel<<<2048, 256, 0, stream>>>(wv, wqkvb + (size_t)20971520, 524288);
    f2b_kernel<<<8192, 256, 0, stream>>>(wo, wob, 2097152);

    // fused QKV projection: (4096, 4096) x (6144, 4096)^T -> (4096, 6144)
    gemm256_bt_kernel<unsigned short><<<384, 512, 0, stream>>>(xb, wqkvb, qkvraw, 4096, 6144, 4096);

    rope_kernel<32><<<4096, 256, 0, stream>>>(qkvraw, cosb, sinb, qrope, 0.08838834764831845f, 0, 6144);
    rope_kernel<8><<<1024, 256, 0, stream>>>(qkvraw, cosb, sinb, krope, 1.0f, 4096, 6144);
    vtrans_kernel<<<512, 256, 0, stream>>>(qkvraw, vt);

    attn_kernel<<<2048, 256, 0, stream>>>(qrope, krope, vt, attnb);

    gemm256_bt_kernel<float><<<256, 512, 0, stream>>>(attnb, wob, out, 4096, 4096, 4096);
}